// Round 8
// baseline (111.832 us; speedup 1.0000x reference)
//
#include <hip/hip_runtime.h>
#include <hip/hip_bf16.h>
#include <math.h>

typedef __attribute__((ext_vector_type(8))) __bf16 bf16x8;
typedef __attribute__((ext_vector_type(4))) float f32x4;

// ws layout (bf16 element offsets). Weights packed in MFMA B-fragment order:
// pack[ks][n][lane][j] = W[k = ks*32 + (lane>>4)*8 + j][col = n*16 + (lane&15)]
#define OFF_W1P    0         // W1 pack [16][8][64][8]
#define OFF_W2P    65536     // W2 pack [4][8][64][8]
#define OFF_W3P    81920     // W3 pack [4][8][64][8]
#define OFF_WINP   98304     // Win pack [4][32][64][8]
#define OFF_WOUTP  163840    // Wout pack [16][8][64][8]
#define NPACK      229376
#define OFF_DH_BYTES 458752  // f32 dh [4096][128] right after the bf16 packs

// Compact tanh-form gelu (abs err ~1e-4 << 0.074 margin)
__device__ __forceinline__ float gelu_f(float x) {
  float t = 1.5957691216f * x * (1.0f + 0.044715f * x * x);
  return __fdividef(x, 1.0f + __expf(-t));
}

__device__ __forceinline__ bf16x8 cvt8(float4 u, float4 v) {
  bf16x8 r;
  r[0] = (__bf16)u.x; r[1] = (__bf16)u.y; r[2] = (__bf16)u.z; r[3] = (__bf16)u.w;
  r[4] = (__bf16)v.x; r[5] = (__bf16)v.y; r[6] = (__bf16)v.z; r[7] = (__bf16)v.w;
  return r;
}

// Async global->LDS, 16B per lane. Dest = wave-uniform base + lane*16.
__device__ __forceinline__ void gload_lds16(const void* g, void* l) {
  __builtin_amdgcn_global_load_lds(
      (const __attribute__((address_space(1))) void*)g,
      (__attribute__((address_space(3))) void*)l, 16, 0, 0);
}

#define MFMA __builtin_amdgcn_mfma_f32_16x16x32_bf16

// ---------------- prep: weight fragment-packing only (bf16) ----------------
__global__ __launch_bounds__(256) void prep_kernel(
    const float* __restrict__ W1, const float* __restrict__ W2,
    const float* __restrict__ W3, const float* __restrict__ Wi,
    const float* __restrict__ Wo, __bf16* __restrict__ wsb)
{
  int i = blockIdx.x * 256 + threadIdx.x;
  float v;
  if (i < 65536) {                    // W1 pack, src W1[512][128]
    int j = i;
    int jj = j & 7, ln = (j >> 3) & 63, n = (j >> 9) & 7, ks = j >> 12;
    int k = ks * 32 + (ln >> 4) * 8 + jj, h = n * 16 + (ln & 15);
    v = W1[k * 128 + h];
  } else if (i < 81920) {             // W2 pack, src W2[128][128]
    int j = i - 65536;
    int jj = j & 7, ln = (j >> 3) & 63, n = (j >> 9) & 7, ks = j >> 12;
    int k = ks * 32 + (ln >> 4) * 8 + jj, g = n * 16 + (ln & 15);
    v = W2[k * 128 + g];
  } else if (i < 98304) {             // W3 pack, src W3[128][128]
    int j = i - 81920;
    int jj = j & 7, ln = (j >> 3) & 63, n = (j >> 9) & 7, ks = j >> 12;
    int k = ks * 32 + (ln >> 4) * 8 + jj, h = n * 16 + (ln & 15);
    v = W3[k * 128 + h];
  } else if (i < 163840) {            // Win pack, src Win[128][512]
    int j = i - 98304;
    int jj = j & 7, ln = (j >> 3) & 63, n = (j >> 9) & 31, ks = j >> 14;
    int k = ks * 32 + (ln >> 4) * 8 + jj, o = n * 16 + (ln & 15);
    v = Wi[k * 512 + o];
  } else {                            // Wout pack, src Wout[512][128]
    int j = i - 163840;
    int jj = j & 7, ln = (j >> 3) & 63, n = (j >> 9) & 7, ks = j >> 12;
    int k = ks * 32 + (ln >> 4) * 8 + jj, h = n * 16 + (ln & 15);
    v = Wo[k * 128 + h];
  }
  wsb[i] = (__bf16)v;
}

// ---------------- kernel 1: fused edge MLP + masked K-reduce ----------------
// block = 2 nodes (96 edge rows), 4 waves; wave w owns output cols
// [w*32,w*32+32) of both nodes -> acc[2][3][2] = 48 VGPRs.
// hE staged F32 via async global_load_lds into dbuf LDS [96][32f32] (12KB x2),
// XOR-swizzled source (rule: linear dest + inv-swz source + swz read).
// Counted vmcnt(3) + raw barriers: next chunk's loads stay in flight; weights
// prefetched one k-step ahead in regs so no use ever drains the stream.
__global__ __launch_bounds__(256, 4) void edge_mlp_kernel(
    const float* __restrict__ hE, const float* __restrict__ hV,
    const float* __restrict__ mask_att, const __bf16* __restrict__ wsb,
    const float* __restrict__ b1, const float* __restrict__ b2,
    const float* __restrict__ b3, float* __restrict__ dh)
{
  __shared__ char lds[24576];   // staging dbuf (2x12288) == X region (96x256B)

  const int tid = threadIdx.x;
  const int w = tid >> 6, lane = tid & 63;
  const int lo = lane & 15, hi = lane >> 4;
  const int n0 = blockIdx.x * 2;

  const __bf16* W1p = wsb + OFF_W1P;

  f32x4 acc[2][3][2];
#pragma unroll
  for (int nl = 0; nl < 2; nl++)
#pragma unroll
    for (int m = 0; m < 3; m++)
#pragma unroll
      for (int nn = 0; nn < 2; nn++) {
        acc[nl][m][nn][0] = 0.f; acc[nl][m][nn][1] = 0.f;
        acc[nl][m][nn][2] = 0.f; acc[nl][m][nn][3] = 0.f;
      }

  // Stage-issue descriptors: 3 issues/thread/chunk, 16B each.
  // Linear LDS offset o = w*3072 + j*1024 + lane*16 -> row r = o>>7 (128B/row),
  // phys unit p = (o>>4)&7; logical unit = p ^ (r&7) (inverse-swizzled source).
  const char* gsrc[3];
  int ldst[3];
#pragma unroll
  for (int j = 0; j < 3; j++) {
    int o = w * 3072 + j * 1024 + lane * 16;
    int r = o >> 7;
    int p = (o >> 4) & 7;
    int lcol = p ^ (r & 7);
    int nl = (r >= 48) ? 1 : 0, kk = r - nl * 48;
    gsrc[j] = (const char*)(hE + (size_t)((n0 + nl) * 48 + kk) * 384 + lcol * 4);
    ldst[j] = w * 3072 + j * 1024;   // wave-uniform dest base
  }

  // issue chunk 0 -> buf0, chunk 1 -> buf1 (oldest outstanding)
#pragma unroll
  for (int j = 0; j < 3; j++) gload_lds16(gsrc[j],       &lds[ldst[j]]);
#pragma unroll
  for (int j = 0; j < 3; j++) gload_lds16(gsrc[j] + 128, &lds[12288 + ldst[j]]);

  // ---- h_V part (k-steps 0..3): broadcast rows, f32 loads + inline cvt ----
#pragma unroll 1
  for (int ks = 0; ks < 4; ++ks) {
    const float* v0 = hV + (n0)     * 128 + ks * 32 + hi * 8;
    const float* v1 = hV + (n0 + 1) * 128 + ks * 32 + hi * 8;
    bf16x8 a0 = cvt8(*(const float4*)v0, *(const float4*)(v0 + 4));
    bf16x8 a1 = cvt8(*(const float4*)v1, *(const float4*)(v1 + 4));
#pragma unroll
    for (int nn = 0; nn < 2; nn++) {
      bf16x8 b = *(const bf16x8*)(W1p + ((ks * 8 + w * 2 + nn) << 9) + lane * 8);
#pragma unroll
      for (int m = 0; m < 3; m++) {
        acc[0][m][nn] = MFMA(a0, b, acc[0][m][nn], 0, 0, 0);
        acc[1][m][nn] = MFMA(a1, b, acc[1][m][nn], 0, 0, 0);
      }
    }
  }

  // weight prefetch for k-step 4 (chunk 0)
  bf16x8 bbc[2], bbn[2];
#pragma unroll
  for (int nn = 0; nn < 2; nn++)
    bbc[nn] = *(const bf16x8*)(W1p + ((4 * 8 + w * 2 + nn) << 9) + lane * 8);

  const int swz0 = (2 * hi) ^ (lo & 7);      // phys unit for logical 2*hi
  const int swz1 = (2 * hi + 1) ^ (lo & 7);  // phys unit for logical 2*hi+1

  // ---- main loop: chunks i=0..11 (k-step 4+i), 2 raw barriers/chunk ----
#pragma unroll 1
  for (int i = 0; i < 12; ++i) {
    // buf[i&1] valid once our chunk-i stages retire; keep chunk i+1's 3 in flight.
    if (i < 11) asm volatile("s_waitcnt vmcnt(3)\n\ts_barrier" ::: "memory");
    else        asm volatile("s_waitcnt vmcnt(0)\n\ts_barrier" ::: "memory");

    // weight prefetch for NEXT chunk (issued before this iter's stage loads)
    if (i < 11) {
#pragma unroll
      for (int nn = 0; nn < 2; nn++)
        bbn[nn] = *(const bf16x8*)(W1p + (((5 + i) * 8 + w * 2 + nn) << 9) + lane * 8);
    }

    // a-frags: read f32 from swizzled LDS, convert to bf16
    const char* Ab = lds + (i & 1) * 12288;
    bf16x8 a[2][3];
#pragma unroll
    for (int nl = 0; nl < 2; nl++)
#pragma unroll
      for (int m = 0; m < 3; m++) {
        int r = nl * 48 + m * 16 + lo;
        const char* rb = Ab + r * 128;
        float4 u = *(const float4*)(rb + swz0 * 16);
        float4 v = *(const float4*)(rb + swz1 * 16);
        a[nl][m] = cvt8(u, v);
      }
#pragma unroll
    for (int nn = 0; nn < 2; nn++)
#pragma unroll
      for (int nl = 0; nl < 2; nl++)
#pragma unroll
        for (int m = 0; m < 3; m++)
          acc[nl][m][nn] = MFMA(a[nl][m], bbc[nn], acc[nl][m][nn], 0, 0, 0);

    // all reads of buf[i&1] done -> safe to overwrite with chunk i+2
    asm volatile("s_waitcnt lgkmcnt(0)\n\ts_barrier" ::: "memory");
    if (i < 10) {
      const int of = (i + 2) * 128;
#pragma unroll
      for (int j = 0; j < 3; j++)
        gload_lds16(gsrc[j] + of, &lds[(i & 1) * 12288 + ldst[j]]);
    }
    if (i < 11) { bbc[0] = bbn[0]; bbc[1] = bbn[1]; }
  }

  // ---- layers 2 and 3: A[96,128] @ W[128,128], X lives in the lds region ----
#pragma unroll 1
  for (int layer = 0; layer < 2; ++layer) {
    const float*  bv = layer ? b2 : b1;
    const __bf16* Wp = wsb + (layer ? OFF_W3P : OFF_W2P);
    __syncthreads();
#pragma unroll
    for (int nn = 0; nn < 2; nn++) {
      int col = (w * 2 + nn) * 16 + lo;
      float bc = bv[col];
#pragma unroll
      for (int nl = 0; nl < 2; nl++)
#pragma unroll
        for (int m = 0; m < 3; m++)
#pragma unroll
          for (int i = 0; i < 4; i++) {
            int row = nl * 48 + m * 16 + hi * 4 + i;
            float g = gelu_f(acc[nl][m][nn][i] + bc);
            *(__bf16*)(lds + row * 256 + ((col * 2) ^ ((row & 7) << 4))) = (__bf16)g;
            acc[nl][m][nn][i] = 0.f;
          }
    }
    __syncthreads();
#pragma unroll 1
    for (int kc2 = 0; kc2 < 2; ++kc2) {
#pragma unroll
      for (int ks32 = 0; ks32 < 2; ++ks32) {
        int ks = kc2 * 2 + ks32;
        bf16x8 bb[2];
#pragma unroll
        for (int nn = 0; nn < 2; nn++)
          bb[nn] = *(const bf16x8*)(Wp + ((ks * 8 + w * 2 + nn) << 9) + lane * 8);
        bf16x8 a[2][3];
#pragma unroll
        for (int nl = 0; nl < 2; nl++)
#pragma unroll
          for (int m = 0; m < 3; m++) {
            int row = nl * 48 + m * 16 + lo;
            a[nl][m] = *(const bf16x8*)(lds + row * 256 + ((kc2 * 128 + ks32 * 64 + hi * 16) ^ ((row & 7) << 4)));
          }
#pragma unroll
        for (int nn = 0; nn < 2; nn++)
#pragma unroll
          for (int nl = 0; nl < 2; nl++)
#pragma unroll
            for (int m = 0; m < 3; m++)
              acc[nl][m][nn] = MFMA(a[nl][m], bb[nn], acc[nl][m][nn], 0, 0, 0);
      }
    }
  }

  // ---- epilogue: + b3, * mask_attend, sum over 48 rows per node, /SCALE ----
#pragma unroll
  for (int nl = 0; nl < 2; nl++) {
    float msk[12];
#pragma unroll
    for (int m = 0; m < 3; m++)
#pragma unroll
      for (int i = 0; i < 4; i++)
        msk[m * 4 + i] = mask_att[(n0 + nl) * 48 + m * 16 + hi * 4 + i];
#pragma unroll
    for (int nn = 0; nn < 2; nn++) {
      int col = (w * 2 + nn) * 16 + lo;
      float bc = b3[col];
      float s = 0.f;
#pragma unroll
      for (int m = 0; m < 3; m++)
#pragma unroll
        for (int i = 0; i < 4; i++)
          s += (acc[nl][m][nn][i] + bc) * msk[m * 4 + i];
      s += __shfl_xor(s, 16);
      s += __shfl_xor(s, 32);
      if (hi == 0)
        dh[(n0 + nl) * 128 + col] = s * (1.0f / 30.0f);
    }
  }
}

// ---------------- kernel 2: LN1 + FFN + LN2 + mask ----------------
// block = 16 nodes, 4 waves
__global__ __launch_bounds__(256, 2) void node_ffn_kernel(
    const float* __restrict__ hV, const float* __restrict__ maskV,
    const __bf16* __restrict__ wsb, const float* __restrict__ dh,
    const float* __restrict__ Winb, const float* __restrict__ Woutb,
    const float* __restrict__ ns1, const float* __restrict__ no1,
    const float* __restrict__ ns2, const float* __restrict__ no2,
    float* __restrict__ out)
{
  __shared__ char lds2[36864];
  char*  xA  = lds2;                    // [16][256B] bf16, swizzled
  float* hvn = (float*)(lds2 + 4096);   // [16][128] f32
  char*  A2  = lds2 + 12288;            // [16][1024B] bf16, swizzled
  float* red = (float*)(lds2 + 28672);  // [16][128] f32

  const __bf16* Winp  = wsb + OFF_WINP;
  const __bf16* Woutp = wsb + OFF_WOUTP;

  const int tid = threadIdx.x;
  const int w = tid >> 6, lane = tid & 63;
  const int lo = lane & 15, hi = lane >> 4;
  const int n0 = blockIdx.x * 16;

  const int row = tid >> 4;
  const int sg  = tid & 15;
  const int node = n0 + row;

  // Phase 0: x = h_V + dh, LN1 -> hvn (f32) and xA (bf16)
  {
    const float* pv = hV + node * 128 + sg * 8;
    const float* pd = dh + node * 128 + sg * 8;
    float4 a0 = *(const float4*)pv;
    float4 a1 = *(const float4*)(pv + 4);
    float4 d0 = *(const float4*)pd;
    float4 d1 = *(const float4*)(pd + 4);
    float x[8] = { a0.x + d0.x, a0.y + d0.y, a0.z + d0.z, a0.w + d0.w,
                   a1.x + d1.x, a1.y + d1.y, a1.z + d1.z, a1.w + d1.w };
    float s = 0.f, sq = 0.f;
#pragma unroll
    for (int j = 0; j < 8; j++) { s += x[j]; sq += x[j] * x[j]; }
#pragma unroll
    for (int off = 8; off >= 1; off >>= 1) { s += __shfl_xor(s, off); sq += __shfl_xor(sq, off); }
    float mean = s * (1.f / 128.f);
    float var  = sq * (1.f / 128.f) - mean * mean;
    float rs = rsqrtf(var + 1e-5f);
    bf16x8 vb;
    float yv[8];
#pragma unroll
    for (int j = 0; j < 8; j++) {
      int col = sg * 8 + j;
      float y = (x[j] - mean) * rs * ns1[col] + no1[col];
      yv[j] = y; vb[j] = (__bf16)y;
    }
    *(float4*)(hvn + row * 128 + sg * 8)     = make_float4(yv[0], yv[1], yv[2], yv[3]);
    *(float4*)(hvn + row * 128 + sg * 8 + 4) = make_float4(yv[4], yv[5], yv[6], yv[7]);
    *(bf16x8*)(xA + row * 256 + ((sg * 16) ^ ((row & 7) << 4))) = vb;
  }
  __syncthreads();

  // Phase 1: [16,128] @ Win -> [16,512]
  f32x4 acc[8];
#pragma unroll
  for (int n = 0; n < 8; n++) { acc[n][0] = 0.f; acc[n][1] = 0.f; acc[n][2] = 0.f; acc[n][3] = 0.f; }
#pragma unroll
  for (int ks = 0; ks < 4; ks++) {
    const int kb = (ks * 32 + hi * 8) * 2;
    bf16x8 a = *(const bf16x8*)(xA + lo * 256 + (kb ^ ((lo & 7) << 4)));
#pragma unroll
    for (int n = 0; n < 8; n++) {
      int ng = w * 8 + n;
      bf16x8 b = *(const bf16x8*)(Winp + ((ks * 32 + ng) << 9) + lane * 8);
      acc[n] = MFMA(a, b, acc[n], 0, 0, 0);
    }
  }
  // Phase 2: gelu -> A2
#pragma unroll
  for (int n = 0; n < 8; n++) {
    int col = w * 128 + n * 16 + lo;
    float bc = Winb[col];
#pragma unroll
    for (int i = 0; i < 4; i++) {
      int r2 = hi * 4 + i;
      float g = gelu_f(acc[n][i] + bc);
      *(__bf16*)(A2 + r2 * 1024 + ((col * 2) ^ ((r2 & 7) << 4))) = (__bf16)g;
    }
  }
  __syncthreads();

  // Phase 3: [16,512] @ Wout -> [16,128]
  f32x4 acc2[2];
  acc2[0][0] = 0.f; acc2[0][1] = 0.f; acc2[0][2] = 0.f; acc2[0][3] = 0.f;
  acc2[1][0] = 0.f; acc2[1][1] = 0.f; acc2[1][2] = 0.f; acc2[1][3] = 0.f;
#pragma unroll
  for (int ks = 0; ks < 16; ks++) {
    const int kb = (ks * 32 + hi * 8) * 2;
    bf16x8 a = *(const bf16x8*)(A2 + lo * 1024 + (kb ^ ((lo & 7) << 4)));
#pragma unroll
    for (int n = 0; n < 2; n++) {
      int ng = w * 2 + n;
      bf16x8 b = *(const bf16x8*)(Woutp + ((ks * 8 + ng) << 9) + lane * 8);
      acc2[n] = MFMA(a, b, acc2[n], 0, 0, 0);
    }
  }
  // Phase 4: + bias -> red
#pragma unroll
  for (int n = 0; n < 2; n++) {
    int col = w * 32 + n * 16 + lo;
    float bc = Woutb[col];
#pragma unroll
    for (int i = 0; i < 4; i++) {
      int r2 = hi * 4 + i;
      red[r2 * 128 + col] = acc2[n][i] + bc;
    }
  }
  __syncthreads();

  // Phase 5: LN2(hvn + red) * mask_V -> out
  {
    const float* ph = hvn + row * 128 + sg * 8;
    const float* pr = red + row * 128 + sg * 8;
    float4 h0 = *(const float4*)ph;
    float4 h1 = *(const float4*)(ph + 4);
    float4 r0 = *(const float4*)pr;
    float4 r1 = *(const float4*)(pr + 4);
    float x[8] = { h0.x + r0.x, h0.y + r0.y, h0.z + r0.z, h0.w + r0.w,
                   h1.x + r1.x, h1.y + r1.y, h1.z + r1.z, h1.w + r1.w };
    float s = 0.f, sq = 0.f;
#pragma unroll
    for (int j = 0; j < 8; j++) { s += x[j]; sq += x[j] * x[j]; }
#pragma unroll
    for (int off = 8; off >= 1; off >>= 1) { s += __shfl_xor(s, off); sq += __shfl_xor(sq, off); }
    float mean = s * (1.f / 128.f);
    float var  = sq * (1.f / 128.f) - mean * mean;
    float rs = rsqrtf(var + 1e-5f);
    float mv = maskV[node];
    float o[8];
#pragma unroll
    for (int j = 0; j < 8; j++) {
      int col = sg * 8 + j;
      o[j] = mv * ((x[j] - mean) * rs * ns2[col] + no2[col]);
    }
    *(float4*)(out + node * 128 + sg * 8)     = make_float4(o[0], o[1], o[2], o[3]);
    *(float4*)(out + node * 128 + sg * 8 + 4) = make_float4(o[4], o[5], o[6], o[7]);
  }
}

extern "C" void kernel_launch(void* const* d_in, const int* in_sizes, int n_in,
                              void* d_out, int out_size, void* d_ws, size_t ws_size,
                              hipStream_t stream)
{
  (void)in_sizes; (void)n_in; (void)out_size; (void)ws_size;
  const float* hV   = (const float*)d_in[0];
  const float* hE   = (const float*)d_in[1];
  const float* mV   = (const float*)d_in[2];
  const float* mAtt = (const float*)d_in[3];
  const float* W1   = (const float*)d_in[4];
  const float* b1   = (const float*)d_in[5];
  const float* W2   = (const float*)d_in[6];
  const float* b2   = (const float*)d_in[7];
  const float* W3   = (const float*)d_in[8];
  const float* b3   = (const float*)d_in[9];
  const float* Win  = (const float*)d_in[10];
  const float* binb = (const float*)d_in[11];
  const float* Wout = (const float*)d_in[12];
  const float* bout = (const float*)d_in[13];
  const float* ns1  = (const float*)d_in[14];
  const float* no1  = (const float*)d_in[15];
  const float* ns2  = (const float*)d_in[16];
  const float* no2  = (const float*)d_in[17];

  __bf16* wsb = (__bf16*)d_ws;
  float* dh   = (float*)((char*)d_ws + OFF_DH_BYTES);
  float* out  = (float*)d_out;

  prep_kernel<<<NPACK / 256, 256, 0, stream>>>(W1, W2, W3, Win, Wout, wsb);
  edge_mlp_kernel<<<2048, 256, 0, stream>>>(hE, hV, mAtt, wsb, b1, b2, b3, dh);
  node_ffn_kernel<<<256, 256, 0, stream>>>(hV, mV, wsb, dh, binb, bout,
                                           ns1, no1, ns2, no2, out);
}